// Round 1
// baseline (164.449 us; speedup 1.0000x reference)
//
#include <hip/hip_runtime.h>
#include <cstdint>
#include <cstddef>

#define NB 8
#define NC 80
#define NH 256
#define NW 256
#define NTOPK 100
#define NBINS 1025          // bin 0 = score < 0.5 underflow; bins 1..1024 cover [0.5,1) at 1/2048
#define CAP 1024
#define PRE_BIN 897         // bin(0.9375): optimistic pre-collect threshold
#define NTHR 256

typedef unsigned long long u64;
typedef unsigned int u32;

__device__ __forceinline__ float sigf(float x) {
    return 1.0f / (1.0f + expf(-x));
}

// scores are sigmoid outputs in (0,1): float bits in (0, 0x3F800000)
__device__ __forceinline__ int score_bin(u32 bits) {
    if (bits < 0x3F000000u) return 0;
    u32 d = bits - 0x3F000000u;
    if (d > 0x7FFFFFu) d = 0x7FFFFFu;
    return 1 + (int)(d >> 13);
}

// total order: score desc, then (class, spatial idx) asc. (c<<16)|sp < 0x500000 <= 0x7FFFFF.
__device__ __forceinline__ u64 make_key(u32 bits, int c, int sp) {
    u32 inv = 0x7FFFFFu ^ (((u32)c << 16) | (u32)sp);
    return ((u64)bits << 23) | (u64)inv;
}

// find highest bin T s.t. count(bins >= T) >= NTOPK (0 if total < NTOPK)
__device__ __forceinline__ void find_binT(const u32* hist, u32* gsum, int* binT_s, int t) {
    if (t < 32) {
        u32 s = 0;
        for (int j = 0; j < 32; ++j) s += hist[1 + t * 32 + j];
        gsum[t] = s;
    }
    __syncthreads();
    if (t == 0) {
        u32 cum = 0;
        int binT = 0;
        for (int g = 31; g >= 0; --g) {
            u32 gs = gsum[g];
            if (cum + gs >= (u32)NTOPK) {
                int bb = 1 + g * 32 + 31;
                for (;; --bb) {
                    cum += hist[bb];
                    if (cum >= (u32)NTOPK) break;
                }
                binT = bb;
                break;
            }
            cum += gs;
        }
        *binT_s = binT;
    }
    __syncthreads();
}

// descending bitonic sort of CAP(=1024) u64 keys in LDS
__device__ __forceinline__ void bitonic_desc(u64* a, int t) {
    for (int k = 2; k <= CAP; k <<= 1) {
        for (int j = k >> 1; j > 0; j >>= 1) {
            for (int i = t; i < CAP; i += NTHR) {
                int p = i ^ j;
                if (p > i) {
                    u64 x = a[i], y = a[p];
                    bool sw = ((i & k) == 0) ? (x < y) : (x > y);
                    if (sw) { a[i] = y; a[p] = x; }
                }
            }
            __syncthreads();
        }
    }
}

// horizontal max-of-3 for 4 consecutive cols held per-lane; col neighbors via shuffles
__device__ __forceinline__ void hmax4(float4 s, int lane, float h[4]) {
    float left  = __shfl_up(s.w, 1);
    float right = __shfl_down(s.x, 1);
    if (lane == 0)  left  = -1.0f;   // x=0 border (any negative < sigmoid)
    if (lane == 63) right = -1.0f;   // x=255 border
    h[0] = fmaxf(fmaxf(left, s.x), s.y);
    h[1] = fmaxf(fmaxf(s.x, s.y), s.z);
    h[2] = fmaxf(fmaxf(s.y, s.z), s.w);
    h[3] = fmaxf(fmaxf(s.z, s.w), right);
}

__device__ __forceinline__ float4 load_sig_row(const float* __restrict__ map, int r, int xb) {
    float4 o;
    if ((unsigned)r > 255u) {
        o.x = o.y = o.z = o.w = -1.0f;   // out-of-range row: -inf stand-in
    } else {
        float4 v = *reinterpret_cast<const float4*>(map + r * NW + xb);
        o.x = sigf(v.x); o.y = sigf(v.y); o.z = sigf(v.z); o.w = sigf(v.w);
    }
    return o;
}

// One block per (b,c) heat map: peak-filter + exact per-class top-100 by composite key.
__global__ __launch_bounds__(NTHR) void k_perclass(const float* __restrict__ hm,
                                                   u64* __restrict__ keys_out) {
    __shared__ u32 hist[NBINS];
    __shared__ u32 bitmap[NH * NW / 32];   // peak bitmap (for rare fallback re-scan)
    __shared__ u64 cand[CAP];
    __shared__ u32 gsum[32];
    __shared__ int cnt_s, binT_s;

    const int t = threadIdx.x;
    const int bc = blockIdx.x;
    const int c = bc % NC;
    const float* __restrict__ map = hm + (size_t)bc * (NH * NW);

    for (int i = t; i < NBINS; i += NTHR) hist[i] = 0;
    for (int i = t; i < NH * NW / 32; i += NTHR) bitmap[i] = 0;
    if (t == 0) cnt_s = 0;
    __syncthreads();

    const int lane = t & 63;
    const int wv = t >> 6;          // wave id 0..3: owns rows [64*wv, 64*wv+64)
    const int xb = lane * 4;        // 4 cols per lane

    // rolling register state: hmax of rows p-1, p, p+1 and sigmoid of row p
    float hm1[4], h0[4], hp1[4];
    float4 scur;
    {
        float4 s = load_sig_row(map, 64 * wv - 1, xb);
        hmax4(s, lane, hm1);
        scur = load_sig_row(map, 64 * wv, xb);
        hmax4(scur, lane, h0);
    }
    for (int p = 64 * wv; p < 64 * wv + 64; ++p) {
        float4 snxt = load_sig_row(map, p + 1, xb);
        hmax4(snxt, lane, hp1);
        const float cv[4] = {scur.x, scur.y, scur.z, scur.w};
#pragma unroll
        for (int j = 0; j < 4; ++j) {
            float m9 = fmaxf(fmaxf(hm1[j], h0[j]), hp1[j]);   // max of 3x3 incl. center
            if (cv[j] >= m9) {                                 // center == window max -> peak
                u32 bits = __float_as_uint(cv[j]);
                int bin = score_bin(bits);
                atomicAdd(&hist[bin], 1u);
                int sp = p * NW + xb + j;
                atomicOr(&bitmap[sp >> 5], 1u << (sp & 31));
                if (bin >= PRE_BIN) {
                    int idx = atomicAdd(&cnt_s, 1);
                    if (idx < CAP) cand[idx] = make_key(bits, c, sp);
                }
            }
        }
#pragma unroll
        for (int j = 0; j < 4; ++j) { hm1[j] = h0[j]; h0[j] = hp1[j]; }
        scur = snxt;
    }
    __syncthreads();

    find_binT(hist, gsum, &binT_s, t);
    int binT = binT_s;
    bool fb = (binT < PRE_BIN) || (cnt_s > CAP);   // pre-collect missed top-100 or overflowed
    if (fb) {
        __syncthreads();
        if (t == 0) cnt_s = 0;
        __syncthreads();
        for (int base = t * 4; base < NH * NW; base += NTHR * 4) {
            float4 v = *reinterpret_cast<const float4*>(map + base);
            const float vv[4] = {v.x, v.y, v.z, v.w};
#pragma unroll
            for (int j = 0; j < 4; ++j) {
                int sp = base + j;
                if ((bitmap[sp >> 5] >> (sp & 31)) & 1u) {
                    u32 bits = __float_as_uint(sigf(vv[j]));
                    if (score_bin(bits) >= binT) {
                        int idx = atomicAdd(&cnt_s, 1);
                        if (idx < CAP) cand[idx] = make_key(bits, c, sp);
                    }
                }
            }
        }
        __syncthreads();
    }
    int nc = cnt_s; if (nc > CAP) nc = CAP;
    for (int i = t; i < CAP; i += NTHR) if (i >= nc) cand[i] = 0ull;
    __syncthreads();
    bitonic_desc(cand, t);
    // first 100 sorted keys == exact per-class top-100 (score desc, sp asc on ties)
    for (int i = t; i < NTOPK; i += NTHR)
        keys_out[(size_t)bc * NTOPK + i] = cand[i];
}

// One block per batch: top-100 of the 8000 per-class keys (global order), decode boxes.
__global__ __launch_bounds__(NTHR) void k_batch(const u64* __restrict__ keys,
                                                const float* __restrict__ wh,
                                                float* __restrict__ out) {
    __shared__ u32 hist[NBINS];
    __shared__ u64 cand[CAP];
    __shared__ u32 gsum[32];
    __shared__ int cnt_s, binT_s;

    const int t = threadIdx.x;
    const int b = blockIdx.x;
    const u64* __restrict__ bk = keys + (size_t)b * (NC * NTOPK);

    for (int i = t; i < NBINS; i += NTHR) hist[i] = 0;
    if (t == 0) cnt_s = 0;
    __syncthreads();
    for (int i = t; i < NC * NTOPK; i += NTHR) {
        u64 key = bk[i];
        if (key) atomicAdd(&hist[score_bin((u32)(key >> 23))], 1u);
    }
    __syncthreads();
    find_binT(hist, gsum, &binT_s, t);
    int binT = binT_s;
    for (int i = t; i < NC * NTOPK; i += NTHR) {
        u64 key = bk[i];
        if (key && score_bin((u32)(key >> 23)) >= binT) {
            int idx = atomicAdd(&cnt_s, 1);
            if (idx < CAP) cand[idx] = key;
        }
    }
    __syncthreads();
    int nc = cnt_s; if (nc > CAP) nc = CAP;
    for (int i = t; i < CAP; i += NTHR) if (i >= nc) cand[i] = 0ull;
    __syncthreads();
    bitonic_desc(cand, t);

    if (t < NTOPK) {
        u64 key = cand[t];
        u32 bits = (u32)(key >> 23);
        float score = __uint_as_float(bits);
        u32 combo = 0x7FFFFFu ^ (u32)(key & 0x7FFFFFu);
        int cc = (int)(combo >> 16);
        int sp = (int)(combo & 0xFFFFu);
        float xs = (float)(sp & 255) * 4.0f;    // STRIDE=4
        float ys = (float)(sp >> 8) * 4.0f;
        const float* wb = wh + (size_t)b * 4 * (NH * NW);
        float w0 = wb[0 * NH * NW + sp];
        float w1 = wb[1 * NH * NW + sp];
        float w2 = wb[2 * NH * NW + sp];
        float w3 = wb[3 * NH * NW + sp];
        bool valid = score > 0.02f;
        float o0 = xs - w0, o1 = ys - w1, o2 = xs + w2, o3 = ys + w3;
        float* op = out + ((size_t)(b * NTOPK + t)) * 6;
        op[0] = valid ? o0 : 0.0f;
        op[1] = valid ? o1 : 0.0f;
        op[2] = valid ? o2 : 0.0f;
        op[3] = valid ? o3 : 0.0f;
        op[4] = valid ? score : 0.0f;
        op[5] = valid ? (float)cc : 0.0f;
    }
}

extern "C" void kernel_launch(void* const* d_in, const int* in_sizes, int n_in,
                              void* d_out, int out_size, void* d_ws, size_t ws_size,
                              hipStream_t stream) {
    (void)in_sizes; (void)n_in; (void)out_size; (void)ws_size;
    const float* hm = (const float*)d_in[0];
    const float* wh = (const float*)d_in[1];
    u64* keys = (u64*)d_ws;   // 640 * 100 * 8B = 512 KB

    hipLaunchKernelGGL(k_perclass, dim3(NB * NC), dim3(NTHR), 0, stream, hm, keys);
    hipLaunchKernelGGL(k_batch, dim3(NB), dim3(NTHR), 0, stream, keys, wh, (float*)d_out);
}